// Round 1
// baseline (783.162 us; speedup 1.0000x reference)
//
#include <hip/hip_runtime.h>

// Problem constants (fixed by setup_inputs)
#define BS   4
#define NH   8
#define SEQ  2048
#define DK   64
#define NP   129   // max_pos + 1
#define WPAD 68    // w/q LDS row pitch (68 % 32 == 4 -> conflict-free row starts; 16B aligned)
#define PPAD 132   // proj LDS row pitch

typedef float v4f __attribute__((ext_vector_type(4)));
typedef int   v4i __attribute__((ext_vector_type(4)));

__global__ __launch_bounds__(256) void pe_fused_kernel(
    const float* __restrict__ q,      // [BS,NH,SEQ,DK]
    const int*   __restrict__ dist,   // [BS,SEQ,SEQ]
    const float* __restrict__ w,      // [NP,DK]
    float*       __restrict__ out)    // [BS,NH,SEQ,SEQ]
{
    __shared__ __align__(16) float w_lds[NP * WPAD];   // 35,088 B
    __shared__ __align__(16) float q_lds[NH * WPAD];   //  2,176 B
    __shared__ __align__(16) float proj[NH * PPAD];    //  4,224 B

    const int tid = threadIdx.x;
    const int bi  = blockIdx.x;        // 0..8191
    const int b   = bi >> 11;
    const int i   = bi & (SEQ - 1);

    // ---- Issue dist-row loads early (independent of LDS phases) ----
    const v4i* dist4 = (const v4i*)(dist + ((size_t)b * SEQ + i) * SEQ);
    const v4i dd0 = __builtin_nontemporal_load(&dist4[tid]);
    const v4i dd1 = __builtin_nontemporal_load(&dist4[256 + tid]);

    // ---- Stage w_rpr into LDS (row pitch WPAD) : 129*16 = 2064 float4 ----
    for (int idx = tid; idx < (NP * DK / 4); idx += 256) {
        const v4f v  = __builtin_nontemporal_load((const v4f*)w + idx);
        const int row = idx >> 4;           // / (DK/4)
        const int c   = (idx & 15) << 2;
        *(v4f*)&w_lds[row * WPAD + c] = v;
    }
    // ---- Stage the 8 q rows for this (b,i) ----
    if (tid < 128) {
        const int h = tid >> 4;
        const int c = (tid & 15) << 2;
        const v4f v = __builtin_nontemporal_load(
            (const v4f*)(q + (((size_t)(b * NH + h)) * SEQ + i) * DK + c));
        *(v4f*)&q_lds[h * WPAD + c] = v;
    }
    __syncthreads();

    // ---- Phase 1: proj[h][p] = q[h] . w[p], 2h x 4p tile per thread ----
    // 4 h-tiles x 33 p-tiles = 132 active threads; p0+j clamped to 128 for
    // loads (branch-free inner loop), store guarded.
    if (tid < 132) {
        const int ht = tid / 33;
        const int pt = tid - ht * 33;
        const int h0 = ht * 2;
        const int p0 = pt * 4;
        const float* qa  = &q_lds[h0 * WPAD];
        const float* qb  = &q_lds[(h0 + 1) * WPAD];
        const float* wr0 = &w_lds[min(p0 + 0, NP - 1) * WPAD];
        const float* wr1 = &w_lds[min(p0 + 1, NP - 1) * WPAD];
        const float* wr2 = &w_lds[min(p0 + 2, NP - 1) * WPAD];
        const float* wr3 = &w_lds[min(p0 + 3, NP - 1) * WPAD];
        float a00 = 0.f, a01 = 0.f, a02 = 0.f, a03 = 0.f;
        float a10 = 0.f, a11 = 0.f, a12 = 0.f, a13 = 0.f;
        #pragma unroll
        for (int d = 0; d < DK; d += 4) {
            const v4f va = *(const v4f*)(qa + d);
            const v4f vb = *(const v4f*)(qb + d);
            const v4f w0 = *(const v4f*)(wr0 + d);
            const v4f w1 = *(const v4f*)(wr1 + d);
            const v4f w2 = *(const v4f*)(wr2 + d);
            const v4f w3 = *(const v4f*)(wr3 + d);
            a00 += va.x*w0.x + va.y*w0.y + va.z*w0.z + va.w*w0.w;
            a01 += va.x*w1.x + va.y*w1.y + va.z*w1.z + va.w*w1.w;
            a02 += va.x*w2.x + va.y*w2.y + va.z*w2.z + va.w*w2.w;
            a03 += va.x*w3.x + va.y*w3.y + va.z*w3.z + va.w*w3.w;
            a10 += vb.x*w0.x + vb.y*w0.y + vb.z*w0.z + vb.w*w0.w;
            a11 += vb.x*w1.x + vb.y*w1.y + vb.z*w1.z + vb.w*w1.w;
            a12 += vb.x*w2.x + vb.y*w2.y + vb.z*w2.z + vb.w*w2.w;
            a13 += vb.x*w3.x + vb.y*w3.y + vb.z*w3.z + vb.w*w3.w;
        }
        proj[(h0    ) * PPAD + p0    ] = a00;
        proj[(h0 + 1) * PPAD + p0    ] = a10;
        if (p0 + 1 < NP) { proj[(h0)*PPAD + p0+1] = a01; proj[(h0+1)*PPAD + p0+1] = a11; }
        if (p0 + 2 < NP) { proj[(h0)*PPAD + p0+2] = a02; proj[(h0+1)*PPAD + p0+2] = a12; }
        if (p0 + 3 < NP) { proj[(h0)*PPAD + p0+3] = a03; proj[(h0+1)*PPAD + p0+3] = a13; }
    }
    __syncthreads();

    // ---- Phase 2: gather + streamed stores ----
    // out[((b*NH+h)*SEQ + i)*SEQ + j]
    const size_t obase = ((size_t)(b * NH) * SEQ + i) * SEQ;
    #pragma unroll
    for (int it = 0; it < 2; ++it) {
        const v4i dd = (it == 0) ? dd0 : dd1;
        const int j0 = (it * 256 + tid) << 2;
        const int px = min(dd.x, NP - 1);
        const int py = min(dd.y, NP - 1);
        const int pz = min(dd.z, NP - 1);
        const int pw = min(dd.w, NP - 1);
        #pragma unroll
        for (int h = 0; h < NH; ++h) {
            const float* pr = &proj[h * PPAD];
            v4f v;
            v.x = pr[px];
            v.y = pr[py];
            v.z = pr[pz];
            v.w = pr[pw];
            __builtin_nontemporal_store(
                v, (v4f*)(out + obase + (size_t)h * ((size_t)SEQ * SEQ) + j0));
        }
    }
}

extern "C" void kernel_launch(void* const* d_in, const int* in_sizes, int n_in,
                              void* d_out, int out_size, void* d_ws, size_t ws_size,
                              hipStream_t stream) {
    const float* q    = (const float*)d_in[0];
    const int*   dist = (const int*)d_in[1];
    const float* w    = (const float*)d_in[2];
    float*       out  = (float*)d_out;

    const int grid = BS * SEQ;  // one block per (b, i) row: 8192 blocks
    pe_fused_kernel<<<grid, 256, 0, stream>>>(q, dist, w, out);
}

// Round 2
// 643.907 us; speedup vs baseline: 1.2163x; 1.2163x over previous
//
#include <hip/hip_runtime.h>

// Problem constants (fixed by setup_inputs)
#define BS   4
#define NH   8
#define SEQ  2048
#define DK   64
#define NP   129      // max_pos + 1
#define QP_PITCH 160  // qp scratch row pitch in floats: 640 B = 5 full cache lines
#define PPAD 132      // proj LDS row pitch

typedef float v4f __attribute__((ext_vector_type(4)));
typedef int   v4i __attribute__((ext_vector_type(4)));

// ---------------------------------------------------------------------------
// Kernel A: qp[r'][p] = dot(q_row(r'), w[p]),  r' = (b*SEQ + i)*NH + h
// Grid: 512 blocks x 256. Even/odd blocks do p in [0,64) / [64,129).
// phalf is block-derived so the w row address is wave-uniform (scalar loads).
// q row lives in 16 v4f registers; 4 independent FMA chains per dot.
// ---------------------------------------------------------------------------
__global__ __launch_bounds__(256) void proj_kernel(
    const float* __restrict__ q,   // [BS,NH,SEQ,DK]
    const float* __restrict__ w,   // [NP,DK]
    float*       __restrict__ qp)  // [BS*SEQ*NH, QP_PITCH]
{
    const int phalf = blockIdx.x & 1;
    const int rp    = ((blockIdx.x >> 1) << 8) + threadIdx.x;  // r' in [0,65536)
    const int h = rp & (NH - 1);
    const int i = (rp >> 3) & (SEQ - 1);
    const int b = rp >> 14;

    const float* qrow = q + (((size_t)(b * NH + h) * SEQ) + i) * DK;
    v4f qreg[16];
    #pragma unroll
    for (int k = 0; k < 16; ++k) qreg[k] = ((const v4f*)qrow)[k];

    float* orow = qp + (size_t)rp * QP_PITCH;
    const int p0 = phalf ? 64 : 0;

    for (int pq = 0; pq < 16; ++pq) {
        v4f acc;
        #pragma unroll
        for (int pp = 0; pp < 4; ++pp) {
            const int p = p0 + pq * 4 + pp;
            const v4f* wrow = (const v4f*)(w + p * DK);
            v4f s = {0.f, 0.f, 0.f, 0.f};
            #pragma unroll
            for (int k = 0; k < 16; ++k) s += qreg[k] * wrow[k];
            acc[pp] = s.x + s.y + s.z + s.w;
        }
        *(v4f*)(orow + p0 + pq * 4) = acc;
    }
    if (phalf) {  // tail position p = 128
        const v4f* wrow = (const v4f*)(w + 128 * DK);
        v4f s = {0.f, 0.f, 0.f, 0.f};
        #pragma unroll
        for (int k = 0; k < 16; ++k) s += qreg[k] * wrow[k];
        orow[128] = s.x + s.y + s.z + s.w;
    }
}

// ---------------------------------------------------------------------------
// Kernel B: one block per (b,i). Stage 8 proj rows (4.2 KB LDS), gather by
// clamped dist, stream 8 output rows with NT float4 stores.
// ---------------------------------------------------------------------------
__global__ __launch_bounds__(256) void gather_kernel(
    const float* __restrict__ qp,    // [BS*SEQ*NH, QP_PITCH]
    const int*   __restrict__ dist,  // [BS,SEQ,SEQ]
    float*       __restrict__ out)   // [BS,NH,SEQ,SEQ]
{
    __shared__ __align__(16) float proj[NH * PPAD];  // 4224 B -> 8 blocks/CU

    const int tid = threadIdx.x;
    const int bi  = blockIdx.x;          // b*SEQ + i
    const int b   = bi >> 11;
    const int i   = bi & (SEQ - 1);

    // Issue dist-row loads early (independent of LDS staging)
    const v4i* dist4 = (const v4i*)(dist + (size_t)bi * SEQ);
    const v4i dd0 = __builtin_nontemporal_load(&dist4[tid]);
    const v4i dd1 = __builtin_nontemporal_load(&dist4[256 + tid]);

    // Stage 8 proj rows: r' base = bi*NH. 8 rows x 33 float4 = 264 slots.
    const float* qpb = qp + (size_t)bi * NH * QP_PITCH;
    for (int t = tid; t < NH * 33; t += 256) {
        const int h = t / 33;
        const int c = t - h * 33;                 // 0..32 -> floats 4c..4c+3 (<=131)
        const v4f v = *(const v4f*)(qpb + h * QP_PITCH + 4 * c);
        *(v4f*)&proj[h * PPAD + 4 * c] = v;
    }
    __syncthreads();

    // Gather + streamed stores: out[((b*NH+h)*SEQ + i)*SEQ + j]
    const size_t obase = ((size_t)(b * NH) * SEQ + i) * SEQ;
    #pragma unroll
    for (int it = 0; it < 2; ++it) {
        const v4i dd = (it == 0) ? dd0 : dd1;
        const int j0 = (it * 256 + tid) << 2;
        const int px = min(dd.x, NP - 1);
        const int py = min(dd.y, NP - 1);
        const int pz = min(dd.z, NP - 1);
        const int pw = min(dd.w, NP - 1);
        #pragma unroll
        for (int h = 0; h < NH; ++h) {
            const float* pr = &proj[h * PPAD];
            v4f v;
            v.x = pr[px];
            v.y = pr[py];
            v.z = pr[pz];
            v.w = pr[pw];
            __builtin_nontemporal_store(
                v, (v4f*)(out + obase + (size_t)h * ((size_t)SEQ * SEQ) + j0));
        }
    }
}

extern "C" void kernel_launch(void* const* d_in, const int* in_sizes, int n_in,
                              void* d_out, int out_size, void* d_ws, size_t ws_size,
                              hipStream_t stream) {
    const float* q    = (const float*)d_in[0];
    const int*   dist = (const int*)d_in[1];
    const float* w    = (const float*)d_in[2];
    float*       out  = (float*)d_out;
    float*       qp   = (float*)d_ws;   // needs 65536 * 160 * 4 = 41.9 MB

    proj_kernel<<<512, 256, 0, stream>>>(q, w, qp);
    gather_kernel<<<BS * SEQ, 256, 0, stream>>>(qp, dist, out);
}